// Round 8
// baseline (197.062 us; speedup 1.0000x reference)
//
#include <hip/hip_runtime.h>

#define B_     16
#define D_     256
#define HEADS_ 8
#define N_     32
#define H_     56
#define W_     56
#define L_     3136

typedef short short8 __attribute__((ext_vector_type(8)));
typedef float f32x4  __attribute__((ext_vector_type(4)));

__device__ __forceinline__ unsigned short f2bf(float f) {
    union { float f; unsigned u; } c; c.f = f;
    unsigned u = c.u;
    u += 0x7fffu + ((u >> 16) & 1u);   // RNE
    return (unsigned short)(u >> 16);
}

// ---------------------------------------------------------------------------
// Wv, Wproj fp32 -> bf16; blockIdx.y==2: qtb[b][16][256] bf16 rows 0..7 =
// q~[b,h,c] = sum_n q[b,hn]*Wk[hn,c], rows 8..15 = 0 (padded MFMA A-operand).
// ---------------------------------------------------------------------------
__global__ __launch_bounds__(256) void convert_w_kernel(
    const float* __restrict__ Wv, const float* __restrict__ Wproj,
    const float* __restrict__ Wk, const float* __restrict__ q,
    unsigned short* __restrict__ Wvb, unsigned short* __restrict__ Wpb,
    unsigned short* __restrict__ qtb)
{
    if (blockIdx.y < 2) {
        const float* src   = (blockIdx.y == 0) ? Wv  : Wproj;
        unsigned short* dst = (blockIdx.y == 0) ? Wvb : Wpb;
        const int i = (blockIdx.x * 256 + threadIdx.x) * 4;
        float4 v = *(const float4*)(src + i);
        uint2 o;
        o.x = (unsigned)f2bf(v.x) | ((unsigned)f2bf(v.y) << 16);
        o.y = (unsigned)f2bf(v.z) | ((unsigned)f2bf(v.w) << 16);
        *(uint2*)(dst + i) = o;
    } else {
        const int b  = blockIdx.x >> 2;
        const int h0 = (blockIdx.x & 3) * 2;
        const int c  = threadIdx.x;
#pragma unroll
        for (int hh = 0; hh < 2; ++hh) {
            const int h = h0 + hh;
            const float* qb = q  + b * D_ + h * N_;
            const float* wr = Wk + (size_t)(h * N_) * D_ + c;
            float acc = 0.f;
#pragma unroll 8
            for (int n = 0; n < N_; ++n)
                acc = fmaf(qb[n], wr[(size_t)n * D_], acc);
            qtb[((size_t)b * 16 + h) * D_ + c]     = f2bf(acc);
            qtb[((size_t)b * 16 + 8 + h) * D_ + c] = 0;
        }
    }
}

// ---------------------------------------------------------------------------
// V = Wv @ x (+ fused S = q~ @ x on wave 0).  Block = 32 l x ALL 256 d.
// Full K-slice of x staged ONCE in LDS as bf16 (16.5 KB, pad-264, swizzled
// write assignment -> ~2-way banks).  K-loop barrier-free: A-frags stream
// from L2-hot Wv.  x fetched exactly once from HBM.
// ---------------------------------------------------------------------------
__global__ __launch_bounds__(256, 4) void gemm_v_mfma(
    const float* __restrict__ x, const unsigned short* __restrict__ Wvb,
    const unsigned short* __restrict__ qtb,
    unsigned short* __restrict__ Vo, float* __restrict__ S)
{
    __shared__ __align__(16) unsigned short Bs[32 * 264];   // 16.5 KB
    unsigned* Bd = (unsigned*)Bs;

    const int t = threadIdx.x;
    const int w = t >> 6, lane = t & 63, col = lane & 15, quad = lane >> 4;
    const int bb = blockIdx.y;
    const int l0 = blockIdx.x * 32;

    // ---- stage x[bb][:, l0..l0+31] -> bf16 LDS [l][c], one shot ----
    {
        const int lg = t & 7;           // l-group of 4
        const int u8 = t >> 3;          // 0..31
        const float* xb = x + (size_t)bb * D_ * L_ + l0 + lg * 4;
#pragma unroll
        for (int s = 0; s < 4; ++s) {
            const int cp = s * 32 + ((u8 + 4 * lg) & 31);   // dword col 0..127
            const float4 a = *(const float4*)(xb + (size_t)(2 * cp) * L_);
            const float4 b = *(const float4*)(xb + (size_t)(2 * cp + 1) * L_);
            unsigned d[4];
            asm("v_cvt_pk_bf16_f32 %0, %1, %2" : "=v"(d[0]) : "v"(a.x), "v"(b.x));
            asm("v_cvt_pk_bf16_f32 %0, %1, %2" : "=v"(d[1]) : "v"(a.y), "v"(b.y));
            asm("v_cvt_pk_bf16_f32 %0, %1, %2" : "=v"(d[2]) : "v"(a.z), "v"(b.z));
            asm("v_cvt_pk_bf16_f32 %0, %1, %2" : "=v"(d[3]) : "v"(a.w), "v"(b.w));
#pragma unroll
            for (int j = 0; j < 4; ++j)
                Bd[(lg * 4 + j) * 132 + cp] = d[j];
        }
    }

    const unsigned short* Ag = Wvb + (size_t)(w * 64 + col) * D_ + quad * 8;
    const unsigned short* qg = qtb + ((size_t)bb * 16 + col) * D_ + quad * 8;

    f32x4 acc[4][2], accS[2];
#pragma unroll
    for (int m = 0; m < 4; ++m)
#pragma unroll
        for (int n = 0; n < 2; ++n) acc[m][n] = (f32x4){0.f, 0.f, 0.f, 0.f};
#pragma unroll
    for (int n = 0; n < 2; ++n) accS[n] = (f32x4){0.f, 0.f, 0.f, 0.f};

    __syncthreads();   // x-tile ready; only barrier in the kernel

#pragma unroll
    for (int kt = 0; kt < 8; ++kt) {
        short8 af[4];
#pragma unroll
        for (int m = 0; m < 4; ++m)
            af[m] = *(const short8*)(Ag + (size_t)m * 16 * D_ + kt * 32);
        short8 bf[2];
#pragma unroll
        for (int n = 0; n < 2; ++n)
            bf[n] = *(const short8*)&Bs[(n * 16 + col) * 264 + kt * 32 + quad * 8];
#pragma unroll
        for (int m = 0; m < 4; ++m)
#pragma unroll
            for (int n = 0; n < 2; ++n)
                acc[m][n] = __builtin_amdgcn_mfma_f32_16x16x32_bf16(
                    af[m], bf[n], acc[m][n], 0, 0, 0);
        if (w == 0) {
            const short8 aq = *(const short8*)(qg + kt * 32);
#pragma unroll
            for (int n = 0; n < 2; ++n)
                accS[n] = __builtin_amdgcn_mfma_f32_16x16x32_bf16(
                    aq, bf[n], accS[n], 0, 0, 0);
        }
    }

    // ---- V epilogue: Vo[b][h][l][32], uint2 stores ----
#pragma unroll
    for (int n = 0; n < 2; ++n) {
        const int l = l0 + n * 16 + col;
#pragma unroll
        for (int m = 0; m < 4; ++m) {
            const int h  = w * 2 + (m >> 1);
            const int dn = (m & 1) * 16 + quad * 4;
            unsigned short ob[4];
#pragma unroll
            for (int r = 0; r < 4; ++r) ob[r] = f2bf(acc[m][n][r]);
            *(uint2*)(Vo + ((size_t)(bb * HEADS_ + h) * L_ + l) * N_ + dn) =
                *(const uint2*)ob;
        }
    }

    // ---- S epilogue (wave 0, rows 0..7 of accS) ----
    if (w == 0 && quad < 2) {
#pragma unroll
        for (int n = 0; n < 2; ++n) {
            const int l = l0 + n * 16 + col;
#pragma unroll
            for (int r = 0; r < 4; ++r)
                S[((size_t)bb * HEADS_ + quad * 4 + r) * L_ + l] = accS[n][r];
        }
    }
}

// ---------------------------------------------------------------------------
// attend v4 (verified): block = (8-row band, b*h), all 32 channels.
// V staged as 600 positions x 64B in LDS with XOR chunk swizzle.
// ---------------------------------------------------------------------------
__global__ __launch_bounds__(256) void attend_kernel(
    const float* __restrict__ S, const unsigned short* __restrict__ Vo,
    const float* __restrict__ pos_emb, const float* __restrict__ Wlin,
    unsigned short* __restrict__ Om)
{
    __shared__ __align__(16) unsigned short Vs[600 * 32];  // 37.5 KB swizzled
    __shared__ float Ss[10][58];                           // 2.3 KB

    const int band = blockIdx.x;   // 0..6
    const int bh   = blockIdx.y;   // 0..127
    const int y0   = band * 8;
    const int t    = threadIdx.x;

    const float* Sb = S + (size_t)bh * L_;
    for (int wi = t; wi < 580; wi += 256) {
        const int row = wi / 58, c = wi - row * 58;
        const int gr = y0 - 1 + row, gc = c - 1;
        float v = 0.f;
        if (gr >= 0 && gr < H_ && gc >= 0 && gc < W_)
            v = Sb[gr * W_ + gc];
        Ss[row][c] = v;
    }

    const unsigned short* Vbase = Vo + (size_t)bh * L_ * N_;
    for (int wi = t; wi < 2400; wi += 256) {
        const int p = wi >> 2, i = wi & 3;
        const int row = p / 60, cc = p - row * 60;
        const int gr = y0 - 1 + row, gc = cc - 1;
        uint4 v = make_uint4(0u, 0u, 0u, 0u);
        if (gr >= 0 && gr < H_ && gc >= 0 && gc < W_)
            v = *(const uint4*)(Vbase + (size_t)(gr * W_ + gc) * N_ + i * 8);
        const int sfc = wi ^ (p & 7);          // swizzled 16B-chunk index
        *(uint4*)(Vs + sfc * 8) = v;
    }
    __syncthreads();

    const float scale = Wlin[0] + Wlin[1] + Wlin[2] + Wlin[3];
    const float pe0 = pos_emb[0], pe1 = pos_emb[1], pe2 = pos_emb[2];
    const float pe3 = pos_emb[3], pe4 = pos_emb[4];
    const float bias[9] = {pe0, pe1, pe2, pe1, pe2, pe3, pe2, pe3, pe4};

    for (int idx = t; idx < 448; idx += 256) {
        const int yl = idx / 56, xx = idx - yl * 56;
        const int lr = yl + 1, lc = xx + 1;

        float lg[9], m = -1e30f;
#pragma unroll
        for (int dy = 0; dy < 3; ++dy)
#pragma unroll
            for (int dx = 0; dx < 3; ++dx) {
                const int k = dy * 3 + dx;
                lg[k] = Ss[lr - 1 + dy][lc - 1 + dx] + bias[k];
                m = fmaxf(m, lg[k]);
            }
        float ssum = 0.f;
#pragma unroll
        for (int k = 0; k < 9; ++k) { lg[k] = __expf(lg[k] - m); ssum += lg[k]; }
        const float inv = scale / ssum;

        float om[32];
#pragma unroll
        for (int i = 0; i < 32; ++i) om[i] = 0.f;

#pragma unroll
        for (int dy = 0; dy < 3; ++dy)
#pragma unroll
            for (int dx = 0; dx < 3; ++dx) {
                const float wk = lg[dy * 3 + dx] * inv;
                const int pos  = (lr - 1 + dy) * 60 + (lc - 1 + dx);
                const int base = pos * 4;
                const int msk  = pos & 7;
#pragma unroll
                for (int i = 0; i < 4; ++i) {
                    const int sfc = (base + i) ^ msk;
                    const uint4 v = *(const uint4*)(Vs + sfc * 8);
                    const unsigned* u = (const unsigned*)&v;
#pragma unroll
                    for (int j = 0; j < 4; ++j) {
                        union { unsigned uu; float f; } lo, hi;
                        lo.uu = u[j] << 16;
                        hi.uu = u[j] & 0xffff0000u;
                        om[i * 8 + 2 * j]     = fmaf(wk, lo.f, om[i * 8 + 2 * j]);
                        om[i * 8 + 2 * j + 1] = fmaf(wk, hi.f, om[i * 8 + 2 * j + 1]);
                    }
                }
            }

        unsigned short ob[32];
#pragma unroll
        for (int i = 0; i < 32; ++i) ob[i] = f2bf(om[i]);
        const int l = (y0 + yl) * W_ + xx;
        uint4* dst = (uint4*)(Om + ((size_t)bh * L_ + l) * N_);
        const uint4* sb = (const uint4*)ob;
#pragma unroll
        for (int i = 0; i < 4; ++i) dst[i] = sb[i];
    }
}

// ---------------------------------------------------------------------------
// out = Wproj @ Om.  Block = 32 l x ALL 256 d; barrier-free K-loop; A and B
// both streamed from cache-hot global (B = one dwordx4/frag, K-chunks=heads);
// 9 KB LDS epilogue -> 1KB-coalesced float4 stores of fp32 out.
// ---------------------------------------------------------------------------
__global__ __launch_bounds__(256, 4) void gemm_proj_mfma(
    const unsigned short* __restrict__ Om, const unsigned short* __restrict__ Wpb,
    float* __restrict__ Out)
{
    __shared__ __align__(16) float Cs[64 * 36];   // 9.2 KB

    const int t = threadIdx.x;
    const int w = t >> 6, lane = t & 63, col = lane & 15, quad = lane >> 4;
    const int bb = blockIdx.y;
    const int l0 = blockIdx.x * 32;

    const unsigned short* Ag = Wpb + (size_t)(w * 64 + col) * D_ + quad * 8;
    const unsigned short* og[2];
#pragma unroll
    for (int n = 0; n < 2; ++n)
        og[n] = Om + ((size_t)(bb * HEADS_) * L_ + l0 + n * 16 + col) * N_ + quad * 8;
    const size_t kstride = (size_t)L_ * N_;

    f32x4 acc[4][2];
#pragma unroll
    for (int m = 0; m < 4; ++m)
#pragma unroll
        for (int n = 0; n < 2; ++n) acc[m][n] = (f32x4){0.f, 0.f, 0.f, 0.f};

#pragma unroll
    for (int kt = 0; kt < 8; ++kt) {
        short8 af[4], bf[2];
#pragma unroll
        for (int m = 0; m < 4; ++m)
            af[m] = *(const short8*)(Ag + (size_t)m * 16 * D_ + kt * 32);
#pragma unroll
        for (int n = 0; n < 2; ++n)
            bf[n] = *(const short8*)(og[n] + (size_t)kt * kstride);
#pragma unroll
        for (int m = 0; m < 4; ++m)
#pragma unroll
            for (int n = 0; n < 2; ++n)
                acc[m][n] = __builtin_amdgcn_mfma_f32_16x16x32_bf16(
                    af[m], bf[n], acc[m][n], 0, 0, 0);
    }

    // ---- LDS-staged epilogue, one 64-row slice per m ----
#pragma unroll
    for (int m = 0; m < 4; ++m) {
        __syncthreads();
#pragma unroll
        for (int n = 0; n < 2; ++n)
#pragma unroll
            for (int r = 0; r < 4; ++r)
                Cs[(w * 16 + quad * 4 + r) * 36 + n * 16 + col] = acc[m][n][r];
        __syncthreads();
#pragma unroll
        for (int i = 0; i < 2; ++i) {
            const int u  = t + i * 256;
            const int lr = u >> 3;            // 0..63
            const int lc = (u & 7) * 4;       // 0..28
            const int d  = (lr >> 4) * 64 + m * 16 + (lr & 15);
            *(float4*)(Out + ((size_t)bb * D_ + d) * L_ + l0 + lc) =
                *(const float4*)&Cs[lr * 36 + lc];
        }
    }
}

// ---------------------------------------------------------------------------
extern "C" void kernel_launch(void* const* d_in, const int* in_sizes, int n_in,
                              void* d_out, int out_size, void* d_ws, size_t ws_size,
                              hipStream_t stream)
{
    const float* x       = (const float*)d_in[0];
    const float* q       = (const float*)d_in[1];
    const float* Wk      = (const float*)d_in[2];
    const float* Wv      = (const float*)d_in[3];
    const float* pos_emb = (const float*)d_in[4];
    const float* Wlin    = (const float*)d_in[5];
    const float* Wproj   = (const float*)d_in[6];
    float* out = (float*)d_out;

    const size_t planeE = (size_t)B_ * D_ * L_;
    unsigned short* Vo  = (unsigned short*)d_ws;
    unsigned short* Om  = Vo + planeE;
    unsigned short* Wvb = Om + planeE;
    unsigned short* Wpb = Wvb + D_ * D_;
    float*          S   = (float*)(Wpb + D_ * D_);
    unsigned short* qtb = (unsigned short*)(S + (size_t)B_ * HEADS_ * L_);

    convert_w_kernel<<<dim3(64, 3), 256, 0, stream>>>(Wv, Wproj, Wk, q, Wvb, Wpb, qtb);
    gemm_v_mfma<<<dim3(L_ / 32, 16), 256, 0, stream>>>(x, Wvb, qtb, Vo, S);
    attend_kernel<<<dim3(7, B_ * HEADS_), 256, 0, stream>>>(S, Vo, pos_emb, Wlin, Om);
    gemm_proj_mfma<<<dim3(L_ / 32, 16), 256, 0, stream>>>(Om, Wpb, out);
}